// Round 6
// baseline (151.472 us; speedup 1.0000x reference)
//
#include <hip/hip_runtime.h>
#include <hip/hip_bf16.h>
#include <stdint.h>

// CAM: out = gamma * (A @ softmax(A^T A)) + x,  A = x.reshape(B, N, C)
// B=32, N=4096 (64*64), C=256.
// Pipeline:
//   K1: symmetric aTa, splitK=4 x 4 row-band WGs per (b,ks); one staged
//       256cx64n LDS tile is BOTH MFMA operands; bands share slab via L2
//       (XCD-pinned).  partials (32MB) -> d_out[64MB..96MB)
//   K2: reduce 4 partials + softmax + transpose -> attnT bf16 (d_ws, 4MB)
//   K3: out = gamma * (A @ attn) + x            (writes all of d_out)

typedef __attribute__((ext_vector_type(8))) short bf16x8s;
typedef __attribute__((ext_vector_type(8))) unsigned short u16x8;
typedef __attribute__((ext_vector_type(4))) float f32x4;
typedef __attribute__((ext_vector_type(4))) float fl4;
typedef __attribute__((ext_vector_type(4))) uint32_t u32x4;
typedef __attribute__((ext_vector_type(2))) uint32_t u32x2;

__device__ __forceinline__ unsigned short f2bf(float f) {
  union { float f; uint32_t u; } v; v.f = f;
  uint32_t r = v.u + 0x7FFFu + ((v.u >> 16) & 1u);
  return (unsigned short)(r >> 16);
}

// packed f32 pair -> 2x bf16 in one u32 (low = lo), RNE
__device__ __forceinline__ uint32_t cvtpk(float lo, float hi) {
  __hip_bfloat162 h = __float22bfloat162_rn(float2{lo, hi});
  union { __hip_bfloat162 h; uint32_t u; } v; v.h = h; return v.u;
}

__device__ __forceinline__ void gload16(const void* g, void* l) {
  __builtin_amdgcn_global_load_lds(
      (const __attribute__((address_space(1))) uint32_t*)g,
      (__attribute__((address_space(3))) uint32_t*)l, 16, 0, 0);
}

// ---------------------------------------------------------------- K1
// aTa[c,d] = sum_n x[n,c]*x[n,d] (symmetric).  Per WG (512 thr, 8 waves):
// 64-row x 256-col band of the Gram, K-slab of 1024 (splitK=4).
// grid = 32*4*4 = 512; XCD-pinned: xcd = d&7 hosts 16 (b,ks) slabs x 4 bands
// = 64 WGs = 2/CU on its 32 CUs; the 4 band-WGs of a slab re-read the same
// x lines L2-hot.  LDS: double-buffered [256 c][64 n] bf16, XOR-swizzled
// byte ^= (row&7)<<4.  T14: issue loads -> MFMA -> cvt+ds_write -> barrier.
__global__ __launch_bounds__(512, 2) void k1_ata(
    const float* __restrict__ x, float* __restrict__ part) {
  __shared__ __align__(16) unsigned short S[2][256 * 64];

  int d = blockIdx.x;                   // 0..511
  int xcd = d & 7, slot = d >> 3;       // slot 0..63
  int band = slot & 3, p = slot >> 2;   // p 0..15
  int gp = xcd * 16 + p;                // 0..127 (b,ks) pairs
  int b = gp >> 2, ks = gp & 3;
  const float* xb = x + ((size_t)b << 20);
  const int nsl = ks * 1024;

  int t = threadIdx.x, w = t >> 6, l = t & 63;
  int wm = w >> 2, wn = w & 3;          // 2x4 wave grid over 64x256
  int fr = l & 15, fh = l >> 4;

  int cb = (t >> 4) * 8;                // staging c-block 0..248
  int nb = (t & 15) * 4;                // staging n-quad 0..60

  f32x4 acc[2][4];
#pragma unroll
  for (int m = 0; m < 2; ++m)
#pragma unroll
    for (int n = 0; n < 4; ++n) acc[m][n] = (f32x4)(0.0f);

  fl4 lo[4], hi[4];                     // 4 n-rows x 8 c each, in flight
  auto LOAD = [&](int kt) {
    const float* s0 = xb + (size_t)(nsl + kt * 64 + nb) * 256 + cb;
#pragma unroll
    for (int r = 0; r < 4; ++r) {
      lo[r] = *(const fl4*)&s0[(size_t)r * 256];
      hi[r] = *(const fl4*)&s0[(size_t)r * 256 + 4];
    }
  };
  auto WRITE = [&](int bsel) {
#pragma unroll
    for (int i = 0; i < 8; ++i) {       // c-row cb+i; (cb+i)&7 == i
      float e0 = (i < 4) ? lo[0][i & 3] : hi[0][i & 3];
      float e1 = (i < 4) ? lo[1][i & 3] : hi[1][i & 3];
      float e2 = (i < 4) ? lo[2][i & 3] : hi[2][i & 3];
      float e3 = (i < 4) ? lo[3][i & 3] : hi[3][i & 3];
      uint32_t w0 = cvtpk(e0, e1), w1 = cvtpk(e2, e3);
      int byt = (cb + i) * 128 + ((nb * 2) ^ (i << 4));
      *(u32x2*)&S[bsel][byt >> 1] = u32x2{w0, w1};
    }
  };

  LOAD(0);
  WRITE(0);
  __syncthreads();

#pragma unroll 1
  for (int kt = 0; kt < 16; ++kt) {
    if (kt < 15) LOAD(kt + 1);
    const unsigned short* Sb = S[kt & 1];
#pragma unroll
    for (int h = 0; h < 2; ++h) {
      bf16x8s afr[2], bfr[4];
#pragma unroll
      for (int m = 0; m < 2; ++m) {
        int row = band * 64 + wm * 32 + m * 16 + fr;
        int byt = row * 128 + ((h * 64 + fh * 16) ^ ((row & 7) << 4));
        afr[m] = *(const bf16x8s*)&Sb[byt >> 1];
      }
#pragma unroll
      for (int n = 0; n < 4; ++n) {
        int row = wn * 64 + n * 16 + fr;
        int byt = row * 128 + ((h * 64 + fh * 16) ^ ((row & 7) << 4));
        bfr[n] = *(const bf16x8s*)&Sb[byt >> 1];
      }
#pragma unroll
      for (int m = 0; m < 2; ++m)
#pragma unroll
        for (int n = 0; n < 4; ++n)
          acc[m][n] = __builtin_amdgcn_mfma_f32_16x16x32_bf16(
              afr[m], bfr[n], acc[m][n], 0, 0, 0);
    }
    if (kt < 15) WRITE((kt + 1) & 1);
    __syncthreads();
  }

  float* pb = part + ((size_t)(b * 4 + ks) << 16);
#pragma unroll
  for (int m = 0; m < 2; ++m) {
    int row = band * 64 + wm * 32 + m * 16 + fh * 4;
#pragma unroll
    for (int n = 0; n < 4; ++n) {
      int col = wn * 64 + n * 16 + fr;
#pragma unroll
      for (int i = 0; i < 4; ++i)
        pb[(size_t)(row + i) * 256 + col] = acc[m][n][i];
    }
  }
}

// ---------------------------------------------------------------- K2
// sum 4 split-K partials, softmax over d, write attnT[b][d][c] (bf16).
// grid = 32*4 = 128 blocks (64 c-rows each), 256 threads (4 waves).
__global__ __launch_bounds__(256) void k2_softmax(
    const float* __restrict__ part, unsigned short* __restrict__ attnT) {
  __shared__ unsigned short T[256][66];
  int d = blockIdx.x;
  int b    = (d & 7) + 8 * ((d >> 3) >> 2);
  int cblk = (d >> 3) & 3;
  int t = threadIdx.x, w = t >> 6, l = t & 63;
  const float* pb = part + ((size_t)b * 4) * 65536 + (size_t)(cblk * 64) * 256;

  for (int it = 0; it < 16; ++it) {
    int c = w * 16 + it;                   // local row 0..63
    float s[4];
#pragma unroll
    for (int i = 0; i < 4; ++i) {
      int dd = l + 64 * i;
      float v = 0.0f;
#pragma unroll
      for (int k = 0; k < 4; ++k)
        v += pb[(size_t)k * 65536 + (size_t)c * 256 + dd];
      s[i] = v;
    }
    float mx = fmaxf(fmaxf(s[0], s[1]), fmaxf(s[2], s[3]));
    for (int off = 32; off; off >>= 1) mx = fmaxf(mx, __shfl_xor(mx, off));
    float sum = 0.0f;
#pragma unroll
    for (int i = 0; i < 4; ++i) { s[i] = __expf(s[i] - mx); sum += s[i]; }
    for (int off = 32; off; off >>= 1) sum += __shfl_xor(sum, off);
    float inv = 1.0f / sum;
#pragma unroll
    for (int i = 0; i < 4; ++i) T[l + 64 * i][c] = f2bf(s[i] * inv);
  }
  __syncthreads();

  unsigned short* ab = attnT + ((size_t)b << 16) + (size_t)t * 256 + cblk * 64;
#pragma unroll
  for (int c8 = 0; c8 < 8; ++c8) {
    u16x8 v;
#pragma unroll
    for (int j = 0; j < 8; ++j) v[j] = T[t][c8 * 8 + j];
    *(u16x8*)&ab[c8 * 8] = v;
  }
}

// ---------------------------------------------------------------- K3
// out[n,d] = gamma * sum_c x[n,c]*attn[c,d] + x[n,d].
// Per WG: 128n x 256d, K=256 in 8 steps of 32.  grid = 32*32 = 1024.
// A: reg-staged f32->bf16 (packed cvt) into swizzled LDS [128][32].
// B: global_load_lds from attnT into swizzled LDS [256][32].
__global__ __launch_bounds__(256, 2) void k3_av(
    const float* __restrict__ x, const unsigned short* __restrict__ attnT,
    const float* __restrict__ gamma, float* __restrict__ out) {
  __shared__ __align__(16) unsigned short A_s[2][128 * 32];
  __shared__ __align__(16) unsigned short B_s[2][256 * 32];

  int dd = blockIdx.x;
  int b  = (dd & 7) + 8 * ((dd >> 3) >> 5);   // XCD swizzle for L2 locality
  int mt = (dd >> 3) & 31;
  int n0 = mt << 7;
  const float* xb = x + ((size_t)b << 20);
  const unsigned short* ab = attnT + ((size_t)b << 16);
  float* ob = out + ((size_t)b << 20);

  int t = threadIdx.x, w = t >> 6, l = t & 63;
  int wm = w >> 1, wn = w & 1;
  int fr = l & 15, fh = l >> 4;

  int ar = t >> 1, ah = t & 1;             // A staging: row, half
  const float* aSrc = xb + (size_t)(n0 + ar) * 256 + ah * 16;
  int brow = l >> 2;                       // B staging: row in 16-row segment
  int bhi = (l & 3) ^ (brow & 3);          // pre-swizzled 16B slot

  f32x4 acc[4][8];
#pragma unroll
  for (int m = 0; m < 4; ++m)
#pragma unroll
    for (int n = 0; n < 8; ++n) acc[m][n] = (f32x4)(0.0f);

  auto STAGE_A = [&](int bsel, int k0) {
    uint32_t pk[8];
#pragma unroll
    for (int q = 0; q < 4; ++q) {
      fl4 v = *(const fl4*)&aSrc[k0 + q * 4];
      pk[2 * q]     = cvtpk(v.x, v.y);
      pk[2 * q + 1] = cvtpk(v.z, v.w);
    }
#pragma unroll
    for (int j = 0; j < 2; ++j) {
      int hi = ah * 2 + j;
      int byt = ar * 64 + ((hi ^ (ar & 3)) << 4);
      *(u32x4*)&A_s[bsel][byt >> 1] =
          u32x4{pk[4 * j], pk[4 * j + 1], pk[4 * j + 2], pk[4 * j + 3]};
    }
  };

  auto STAGE_B = [&](int bsel, int k0) {
#pragma unroll
    for (int r = 0; r < 4; ++r) {
      int seg = r * 4 + w;                 // 16 segments of 16 rows
      int row = seg * 16 + brow;
      gload16(&ab[(size_t)row * 256 + k0 + bhi * 8], &B_s[bsel][seg * 512]);
    }
  };

  STAGE_A(0, 0);
  STAGE_B(0, 0);
  __syncthreads();

  int buf = 0;
#pragma unroll 1
  for (int kt = 0; kt < 8; ++kt) {
    if (kt < 7) { STAGE_A(buf ^ 1, (kt + 1) * 32); STAGE_B(buf ^ 1, (kt + 1) * 32); }
    bf16x8s af[4];
#pragma unroll
    for (int m = 0; m < 4; ++m) {
      int row = wm * 64 + m * 16 + fr;
      int byt = row * 64 + ((fh ^ (row & 3)) << 4);
      af[m] = *(const bf16x8s*)&A_s[buf][byt >> 1];
    }
    bf16x8s bf[8];
#pragma unroll
    for (int n = 0; n < 8; ++n) {
      int dn = wn * 128 + n * 16 + fr;
      int byt = dn * 64 + ((fh ^ (dn & 3)) << 4);
      bf[n] = *(const bf16x8s*)&B_s[buf][byt >> 1];
    }
#pragma unroll
    for (int m = 0; m < 4; ++m)
#pragma unroll
      for (int n = 0; n < 8; ++n)
        acc[m][n] = __builtin_amdgcn_mfma_f32_16x16x32_bf16(
            af[m], bf[n], acc[m][n], 0, 0, 0);
    __syncthreads();
    buf ^= 1;
  }

  float g = gamma[0];
#pragma unroll
  for (int m = 0; m < 4; ++m) {
    int row = wm * 64 + m * 16 + fh * 4;
#pragma unroll
    for (int n = 0; n < 8; ++n) {
      int col = wn * 128 + n * 16 + fr;
#pragma unroll
      for (int i = 0; i < 4; ++i) {
        size_t idx = (size_t)(n0 + row + i) * 256 + col;
        ob[idx] = g * acc[m][n][i] + xb[idx];
      }
    }
  }
}

// ---------------------------------------------------------------- launch
extern "C" void kernel_launch(void* const* d_in, const int* in_sizes, int n_in,
                              void* d_out, int out_size, void* d_ws, size_t ws_size,
                              hipStream_t stream) {
  const float* x     = (const float*)d_in[0];
  const float* gamma = (const float*)d_in[1];
  float* out = (float*)d_out;

  // scratch layout: partials (32MB) live in d_out[64MB..96MB) (dead before K3
  // rewrites it); attnT (4MB) in d_ws (K3 reads it while writing d_out).
  float*          part  = (float*)((char*)d_out + (size_t)64 * 1024 * 1024);
  unsigned short* attnT = (unsigned short*)d_ws;

  k1_ata<<<512, 512, 0, stream>>>(x, part);
  k2_softmax<<<128, 256, 0, stream>>>(part, attnT);
  k3_av<<<1024, 256, 0, stream>>>(x, attnT, gamma, out);
}

// Round 7
// 117.230 us; speedup vs baseline: 1.2921x; 1.2921x over previous
//
#include <hip/hip_runtime.h>
#include <hip/hip_bf16.h>
#include <stdint.h>

// CAM: out = gamma * (A @ softmax(A^T A)) + x,  A = x.reshape(B, N, C)
// B=32, N=4096 (64*64), C=256.
// Pipeline:
//   K1: symmetric aTa, splitK=8; one WG per (b,ks) stages a 256c x 64n slab
//       per kt with COALESCED row loads (wave = 1KB row/instr) + in-lane
//       8x4 transpose -> swizzled LDS; the tile is BOTH MFMA operands.
//       partials (64MB) -> d_out[64MB..128MB)
//   K2: reduce 8 partials + softmax + transpose -> attnT bf16 (d_ws, 4MB)
//   K3: out = gamma * (A @ attn) + x            (writes all of d_out)

typedef __attribute__((ext_vector_type(8))) short bf16x8s;
typedef __attribute__((ext_vector_type(8))) unsigned short u16x8;
typedef __attribute__((ext_vector_type(4))) float f32x4;
typedef __attribute__((ext_vector_type(4))) float fl4;
typedef __attribute__((ext_vector_type(4))) uint32_t u32x4;

__device__ __forceinline__ unsigned short f2bf(float f) {
  union { float f; uint32_t u; } v; v.f = f;
  uint32_t r = v.u + 0x7FFFu + ((v.u >> 16) & 1u);
  return (unsigned short)(r >> 16);
}

// packed f32 pair -> 2x bf16 in one u32 (low = lo), RNE
__device__ __forceinline__ uint32_t cvtpk(float lo, float hi) {
  __hip_bfloat162 h = __float22bfloat162_rn(float2{lo, hi});
  union { __hip_bfloat162 h; uint32_t u; } v; v.h = h; return v.u;
}

__device__ __forceinline__ void gload16(const void* g, void* l) {
  __builtin_amdgcn_global_load_lds(
      (const __attribute__((address_space(1))) uint32_t*)g,
      (__attribute__((address_space(3))) uint32_t*)l, 16, 0, 0);
}

// ---------------------------------------------------------------- K1
// aTa[c,d] = sum_n x[n,c]*x[n,d] (symmetric): stage ONE 256c x 64n bf16 tile,
// use it as both A and B.  Per WG (512 thr, 8 waves): full 256x256 output,
// K-slab of 512 (splitK=8).  grid = 32*8 = 256 (1/CU); x read exactly once.
// Staging per kt: wave w, instr j: lane l loads fl4 at (row w*8+j, col 4l)
// -> 1KB fully-coalesced row per instruction.  Lane then holds an 8n x 4c
// block; reg-transpose + cvtpk -> 4x ds_write_b128 (8 n-values per c-row)
// into XOR-swizzled LDS ([256 c][64 n] bf16, byte ^= (row&7)<<4) — identical
// layout to the MFMA fragment reads.  T14: LOAD(kt+1) -> MFMA -> WRITE -> bar.
__global__ __launch_bounds__(512, 2) void k1_ata(
    const float* __restrict__ x, float* __restrict__ part) {
  __shared__ __align__(16) unsigned short S[2][256 * 64];

  int bid = blockIdx.x;                 // 0..255
  int b = bid >> 3, ks = bid & 7;
  const float* xb = x + ((size_t)b << 20);
  const int nsl = ks * 512;

  int t = threadIdx.x, w = t >> 6, l = t & 63;
  int wm = w >> 1, wn = w & 1;          // 4x2 wave grid: 64-row x 128-col
  int fr = l & 15, fh = l >> 4;

  f32x4 acc[4][8];
#pragma unroll
  for (int m = 0; m < 4; ++m)
#pragma unroll
    for (int n = 0; n < 8; ++n) acc[m][n] = (f32x4)(0.0f);

  fl4 v[8];                             // rows w*8+j, cols [4l,4l+4)
  auto LOAD = [&](int kt) {
    const float* s0 = xb + (size_t)(nsl + kt * 64 + w * 8) * 256 + 4 * l;
#pragma unroll
    for (int j = 0; j < 8; ++j) v[j] = *(const fl4*)&s0[(size_t)j * 256];
  };
  auto WRITE = [&](int bsel) {
#pragma unroll
    for (int i = 0; i < 4; ++i) {
      int c = 4 * l + i;
      uint32_t w0 = cvtpk(v[0][i], v[1][i]);
      uint32_t w1 = cvtpk(v[2][i], v[3][i]);
      uint32_t w2 = cvtpk(v[4][i], v[5][i]);
      uint32_t w3 = cvtpk(v[6][i], v[7][i]);
      int byt = c * 128 + ((w * 16) ^ ((c & 7) << 4));
      *(u32x4*)&S[bsel][byt >> 1] = u32x4{w0, w1, w2, w3};
    }
  };

  LOAD(0);
  WRITE(0);
  __syncthreads();

#pragma unroll 1
  for (int kt = 0; kt < 8; ++kt) {
    if (kt < 7) LOAD(kt + 1);
    const unsigned short* Sb = S[kt & 1];
#pragma unroll
    for (int h = 0; h < 2; ++h) {
      bf16x8s afr[4], bfr[8];
#pragma unroll
      for (int m = 0; m < 4; ++m) {
        int row = wm * 64 + m * 16 + fr;
        int byt = row * 128 + ((h * 64 + fh * 16) ^ ((row & 7) << 4));
        afr[m] = *(const bf16x8s*)&Sb[byt >> 1];
      }
#pragma unroll
      for (int n = 0; n < 8; ++n) {
        int row = wn * 128 + n * 16 + fr;
        int byt = row * 128 + ((h * 64 + fh * 16) ^ ((row & 7) << 4));
        bfr[n] = *(const bf16x8s*)&Sb[byt >> 1];
      }
#pragma unroll
      for (int m = 0; m < 4; ++m)
#pragma unroll
        for (int n = 0; n < 8; ++n)
          acc[m][n] = __builtin_amdgcn_mfma_f32_16x16x32_bf16(
              afr[m], bfr[n], acc[m][n], 0, 0, 0);
    }
    if (kt < 7) WRITE((kt + 1) & 1);
    __syncthreads();
  }

  float* pb = part + ((size_t)bid << 16);   // bid = b*8+ks, 256KB partial
#pragma unroll
  for (int m = 0; m < 4; ++m) {
    int row = wm * 64 + m * 16 + fh * 4;
#pragma unroll
    for (int n = 0; n < 8; ++n) {
      int col = wn * 128 + n * 16 + fr;
#pragma unroll
      for (int i = 0; i < 4; ++i)
        pb[(size_t)(row + i) * 256 + col] = acc[m][n][i];
    }
  }
}

// ---------------------------------------------------------------- K2
// sum 8 split-K partials, softmax over d, write attnT[b][d][c] (bf16).
// grid = 32*4 = 128 blocks (64 c-rows each), 256 threads (4 waves).
__global__ __launch_bounds__(256) void k2_softmax(
    const float* __restrict__ part, unsigned short* __restrict__ attnT) {
  __shared__ unsigned short T[256][66];
  int d = blockIdx.x;
  int b    = (d & 7) + 8 * ((d >> 3) >> 2);
  int cblk = (d >> 3) & 3;
  int t = threadIdx.x, w = t >> 6, l = t & 63;
  const float* pb = part + ((size_t)b * 8) * 65536 + (size_t)(cblk * 64) * 256;

  for (int it = 0; it < 16; ++it) {
    int c = w * 16 + it;                   // local row 0..63
    float s[4];
#pragma unroll
    for (int i = 0; i < 4; ++i) {
      int dd = l + 64 * i;
      float vv = 0.0f;
#pragma unroll
      for (int k = 0; k < 8; ++k)
        vv += pb[(size_t)k * 65536 + (size_t)c * 256 + dd];
      s[i] = vv;
    }
    float mx = fmaxf(fmaxf(s[0], s[1]), fmaxf(s[2], s[3]));
    for (int off = 32; off; off >>= 1) mx = fmaxf(mx, __shfl_xor(mx, off));
    float sum = 0.0f;
#pragma unroll
    for (int i = 0; i < 4; ++i) { s[i] = __expf(s[i] - mx); sum += s[i]; }
    for (int off = 32; off; off >>= 1) sum += __shfl_xor(sum, off);
    float inv = 1.0f / sum;
#pragma unroll
    for (int i = 0; i < 4; ++i) T[l + 64 * i][c] = f2bf(s[i] * inv);
  }
  __syncthreads();

  unsigned short* ab = attnT + ((size_t)b << 16) + (size_t)t * 256 + cblk * 64;
#pragma unroll
  for (int c8 = 0; c8 < 8; ++c8) {
    u16x8 vv;
#pragma unroll
    for (int j = 0; j < 8; ++j) vv[j] = T[t][c8 * 8 + j];
    *(u16x8*)&ab[c8 * 8] = vv;
  }
}

// ---------------------------------------------------------------- K3
// out[n,d] = gamma * sum_c x[n,c]*attn[c,d] + x[n,d].
// Per WG: 128n x 256d, K=256 in 8 steps of 32.  grid = 32*32 = 1024.
// A: reg-staged f32->bf16 (packed cvt) into swizzled LDS [128][32].
// B: global_load_lds from attnT into swizzled LDS [256][32].
__global__ __launch_bounds__(256, 2) void k3_av(
    const float* __restrict__ x, const unsigned short* __restrict__ attnT,
    const float* __restrict__ gamma, float* __restrict__ out) {
  __shared__ __align__(16) unsigned short A_s[2][128 * 32];
  __shared__ __align__(16) unsigned short B_s[2][256 * 32];

  int dd = blockIdx.x;
  int b  = (dd & 7) + 8 * ((dd >> 3) >> 5);   // XCD swizzle for L2 locality
  int mt = (dd >> 3) & 31;
  int n0 = mt << 7;
  const float* xb = x + ((size_t)b << 20);
  const unsigned short* ab = attnT + ((size_t)b << 16);
  float* ob = out + ((size_t)b << 20);

  int t = threadIdx.x, w = t >> 6, l = t & 63;
  int wm = w >> 1, wn = w & 1;
  int fr = l & 15, fh = l >> 4;

  int ar = t >> 1, ah = t & 1;             // A staging: row, half
  const float* aSrc = xb + (size_t)(n0 + ar) * 256 + ah * 16;
  int brow = l >> 2;                       // B staging: row in 16-row segment
  int bhi = (l & 3) ^ (brow & 3);          // pre-swizzled 16B slot

  f32x4 acc[4][8];
#pragma unroll
  for (int m = 0; m < 4; ++m)
#pragma unroll
    for (int n = 0; n < 8; ++n) acc[m][n] = (f32x4)(0.0f);

  auto STAGE_A = [&](int bsel, int k0) {
    uint32_t pk[8];
#pragma unroll
    for (int q = 0; q < 4; ++q) {
      fl4 vv = *(const fl4*)&aSrc[k0 + q * 4];
      pk[2 * q]     = cvtpk(vv.x, vv.y);
      pk[2 * q + 1] = cvtpk(vv.z, vv.w);
    }
#pragma unroll
    for (int j = 0; j < 2; ++j) {
      int hi = ah * 2 + j;
      int byt = ar * 64 + ((hi ^ (ar & 3)) << 4);
      *(u32x4*)&A_s[bsel][byt >> 1] =
          u32x4{pk[4 * j], pk[4 * j + 1], pk[4 * j + 2], pk[4 * j + 3]};
    }
  };

  auto STAGE_B = [&](int bsel, int k0) {
#pragma unroll
    for (int r = 0; r < 4; ++r) {
      int seg = r * 4 + w;                 // 16 segments of 16 rows
      int row = seg * 16 + brow;
      gload16(&ab[(size_t)row * 256 + k0 + bhi * 8], &B_s[bsel][seg * 512]);
    }
  };

  STAGE_A(0, 0);
  STAGE_B(0, 0);
  __syncthreads();

  int buf = 0;
#pragma unroll 1
  for (int kt = 0; kt < 8; ++kt) {
    if (kt < 7) { STAGE_A(buf ^ 1, (kt + 1) * 32); STAGE_B(buf ^ 1, (kt + 1) * 32); }
    bf16x8s af[4];
#pragma unroll
    for (int m = 0; m < 4; ++m) {
      int row = wm * 64 + m * 16 + fr;
      int byt = row * 64 + ((fh ^ (row & 3)) << 4);
      af[m] = *(const bf16x8s*)&A_s[buf][byt >> 1];
    }
    bf16x8s bfv[8];
#pragma unroll
    for (int n = 0; n < 8; ++n) {
      int dn = wn * 128 + n * 16 + fr;
      int byt = dn * 64 + ((fh ^ (dn & 3)) << 4);
      bfv[n] = *(const bf16x8s*)&B_s[buf][byt >> 1];
    }
#pragma unroll
    for (int m = 0; m < 4; ++m)
#pragma unroll
      for (int n = 0; n < 8; ++n)
        acc[m][n] = __builtin_amdgcn_mfma_f32_16x16x32_bf16(
            af[m], bfv[n], acc[m][n], 0, 0, 0);
    __syncthreads();
    buf ^= 1;
  }

  float g = gamma[0];
#pragma unroll
  for (int m = 0; m < 4; ++m) {
    int row = wm * 64 + m * 16 + fh * 4;
#pragma unroll
    for (int n = 0; n < 8; ++n) {
      int col = wn * 128 + n * 16 + fr;
#pragma unroll
      for (int i = 0; i < 4; ++i) {
        size_t idx = (size_t)(n0 + row + i) * 256 + col;
        ob[idx] = g * acc[m][n][i] + xb[idx];
      }
    }
  }
}

// ---------------------------------------------------------------- launch
extern "C" void kernel_launch(void* const* d_in, const int* in_sizes, int n_in,
                              void* d_out, int out_size, void* d_ws, size_t ws_size,
                              hipStream_t stream) {
  const float* x     = (const float*)d_in[0];
  const float* gamma = (const float*)d_in[1];
  float* out = (float*)d_out;

  // scratch layout: partials (64MB) live in d_out[64MB..128MB) (dead before K3
  // rewrites it); attnT (4MB) in d_ws (K3 reads it while writing d_out).
  float*          part  = (float*)((char*)d_out + (size_t)64 * 1024 * 1024);
  unsigned short* attnT = (unsigned short*)d_ws;

  k1_ata<<<256, 512, 0, stream>>>(x, part);
  k2_softmax<<<128, 256, 0, stream>>>(part, attnT);
  k3_av<<<1024, 256, 0, stream>>>(x, attnT, gamma, out);
}

// Round 8
// 112.567 us; speedup vs baseline: 1.3456x; 1.0414x over previous
//
#include <hip/hip_runtime.h>
#include <hip/hip_bf16.h>
#include <stdint.h>

// CAM: out = gamma * (A @ softmax(A^T A)) + x,  A = x.reshape(B, N, C)
// B=32, N=4096 (64*64), C=256.
// Pipeline:
//   K1: symmetric aTa, splitK=8; one WG per (b,ks) stages a 256c x 64n slab
//       per kt with coalesced row loads + in-lane transpose -> swizzled LDS;
//       tile is BOTH MFMA operands.  partials now BF16 (32MB) -> d_out[64MB..96MB)
//   K2: reduce 8 bf16 partials + softmax + transpose -> attnT bf16 (d_ws, 4MB)
//   K3: out = gamma * (A @ attn) + x            (writes all of d_out)

typedef __attribute__((ext_vector_type(8))) short bf16x8s;
typedef __attribute__((ext_vector_type(8))) unsigned short u16x8;
typedef __attribute__((ext_vector_type(4))) unsigned short u16x4;
typedef __attribute__((ext_vector_type(4))) float f32x4;
typedef __attribute__((ext_vector_type(4))) float fl4;
typedef __attribute__((ext_vector_type(4))) uint32_t u32x4;

__device__ __forceinline__ unsigned short f2bf(float f) {
  union { float f; uint32_t u; } v; v.f = f;
  uint32_t r = v.u + 0x7FFFu + ((v.u >> 16) & 1u);
  return (unsigned short)(r >> 16);
}

__device__ __forceinline__ float bf2f(unsigned short h) {
  union { float f; uint32_t u; } v; v.u = ((uint32_t)h) << 16; return v.f;
}

// packed f32 pair -> 2x bf16 in one u32 (low = lo), RNE
__device__ __forceinline__ uint32_t cvtpk(float lo, float hi) {
  __hip_bfloat162 h = __float22bfloat162_rn(float2{lo, hi});
  union { __hip_bfloat162 h; uint32_t u; } v; v.h = h; return v.u;
}

__device__ __forceinline__ void gload16(const void* g, void* l) {
  __builtin_amdgcn_global_load_lds(
      (const __attribute__((address_space(1))) uint32_t*)g,
      (__attribute__((address_space(3))) uint32_t*)l, 16, 0, 0);
}

// ---------------------------------------------------------------- K1
// aTa[c,d] = sum_n x[n,c]*x[n,d] (symmetric): stage ONE 256c x 64n bf16 tile,
// use it as both A and B.  Per WG (512 thr, 8 waves): full 256x256 output,
// K-slab of 512 (splitK=8).  grid = 32*8 = 256 (1/CU); x read exactly once.
// Staging per kt: wave w, instr j: lane l loads fl4 at (row w*8+j, col 4l)
// -> 1KB fully-coalesced row per instruction; lane reg-transposes its 8n x 4c
// block, cvtpk -> 4x ds_write_b128 into XOR-swizzled LDS
// ([256 c][64 n] bf16, byte ^= (row&7)<<4).  T14: LOAD(kt+1)->MFMA->WRITE->bar.
// Partials stored BF16 (halves the split-K round-trip traffic; logit gap
// diag-offdiag ~3900 makes the softmax insensitive to bf16 rounding).
__global__ __launch_bounds__(512, 2) void k1_ata(
    const float* __restrict__ x, unsigned short* __restrict__ part) {
  __shared__ __align__(16) unsigned short S[2][256 * 64];

  int bid = blockIdx.x;                 // 0..255
  int b = bid >> 3, ks = bid & 7;
  const float* xb = x + ((size_t)b << 20);
  const int nsl = ks * 512;

  int t = threadIdx.x, w = t >> 6, l = t & 63;
  int wm = w >> 1, wn = w & 1;          // 4x2 wave grid: 64-row x 128-col
  int fr = l & 15, fh = l >> 4;

  f32x4 acc[4][8];
#pragma unroll
  for (int m = 0; m < 4; ++m)
#pragma unroll
    for (int n = 0; n < 8; ++n) acc[m][n] = (f32x4)(0.0f);

  fl4 v[8];                             // rows w*8+j, cols [4l,4l+4)
  auto LOAD = [&](int kt) {
    const float* s0 = xb + (size_t)(nsl + kt * 64 + w * 8) * 256 + 4 * l;
#pragma unroll
    for (int j = 0; j < 8; ++j) v[j] = *(const fl4*)&s0[(size_t)j * 256];
  };
  auto WRITE = [&](int bsel) {
#pragma unroll
    for (int i = 0; i < 4; ++i) {
      int c = 4 * l + i;
      uint32_t w0 = cvtpk(v[0][i], v[1][i]);
      uint32_t w1 = cvtpk(v[2][i], v[3][i]);
      uint32_t w2 = cvtpk(v[4][i], v[5][i]);
      uint32_t w3 = cvtpk(v[6][i], v[7][i]);
      int byt = c * 128 + ((w * 16) ^ ((c & 7) << 4));
      *(u32x4*)&S[bsel][byt >> 1] = u32x4{w0, w1, w2, w3};
    }
  };

  LOAD(0);
  WRITE(0);
  __syncthreads();

#pragma unroll 1
  for (int kt = 0; kt < 8; ++kt) {
    if (kt < 7) LOAD(kt + 1);
    const unsigned short* Sb = S[kt & 1];
#pragma unroll
    for (int h = 0; h < 2; ++h) {
      bf16x8s afr[4], bfr[8];
#pragma unroll
      for (int m = 0; m < 4; ++m) {
        int row = wm * 64 + m * 16 + fr;
        int byt = row * 128 + ((h * 64 + fh * 16) ^ ((row & 7) << 4));
        afr[m] = *(const bf16x8s*)&Sb[byt >> 1];
      }
#pragma unroll
      for (int n = 0; n < 8; ++n) {
        int row = wn * 128 + n * 16 + fr;
        int byt = row * 128 + ((h * 64 + fh * 16) ^ ((row & 7) << 4));
        bfr[n] = *(const bf16x8s*)&Sb[byt >> 1];
      }
#pragma unroll
      for (int m = 0; m < 4; ++m)
#pragma unroll
        for (int n = 0; n < 8; ++n)
          acc[m][n] = __builtin_amdgcn_mfma_f32_16x16x32_bf16(
              afr[m], bfr[n], acc[m][n], 0, 0, 0);
    }
    if (kt < 7) WRITE((kt + 1) & 1);
    __syncthreads();
  }

  unsigned short* pb = part + ((size_t)bid << 16);  // bid = b*8+ks, 128KB bf16
#pragma unroll
  for (int m = 0; m < 4; ++m) {
    int row = wm * 64 + m * 16 + fh * 4;
#pragma unroll
    for (int n = 0; n < 8; ++n) {
      int col = wn * 128 + n * 16 + fr;
#pragma unroll
      for (int i = 0; i < 4; ++i)
        pb[(size_t)(row + i) * 256 + col] = f2bf(acc[m][n][i]);
    }
  }
}

// ---------------------------------------------------------------- K2
// sum 8 bf16 split-K partials, softmax over d, write attnT[b][d][c] (bf16).
// grid = 32*4 = 128 blocks (64 c-rows each), 256 threads (4 waves).
// Lane l owns cols 4l..4l+3 -> u16x4 contiguous loads (512B/wave/instr).
__global__ __launch_bounds__(256) void k2_softmax(
    const unsigned short* __restrict__ part, unsigned short* __restrict__ attnT) {
  __shared__ unsigned short T[256][66];
  int d = blockIdx.x;
  int b    = (d & 7) + 8 * ((d >> 3) >> 2);
  int cblk = (d >> 3) & 3;
  int t = threadIdx.x, w = t >> 6, l = t & 63;
  const unsigned short* pb =
      part + ((size_t)(b * 8) << 16) + (size_t)(cblk * 64) * 256 + 4 * l;

  for (int it = 0; it < 16; ++it) {
    int c = w * 16 + it;                   // local row 0..63
    float s[4] = {0.f, 0.f, 0.f, 0.f};
#pragma unroll
    for (int k = 0; k < 8; ++k) {
      u16x4 vv = *(const u16x4*)&pb[((size_t)k << 16) + (size_t)c * 256];
#pragma unroll
      for (int i = 0; i < 4; ++i) s[i] += bf2f(vv[i]);
    }
    float mx = fmaxf(fmaxf(s[0], s[1]), fmaxf(s[2], s[3]));
    for (int off = 32; off; off >>= 1) mx = fmaxf(mx, __shfl_xor(mx, off));
    float sum = 0.0f;
#pragma unroll
    for (int i = 0; i < 4; ++i) { s[i] = __expf(s[i] - mx); sum += s[i]; }
    for (int off = 32; off; off >>= 1) sum += __shfl_xor(sum, off);
    float inv = 1.0f / sum;
#pragma unroll
    for (int i = 0; i < 4; ++i) T[4 * l + i][c] = f2bf(s[i] * inv);
  }
  __syncthreads();

  unsigned short* ab = attnT + ((size_t)b << 16) + (size_t)t * 256 + cblk * 64;
#pragma unroll
  for (int c8 = 0; c8 < 8; ++c8) {
    u16x8 vv;
#pragma unroll
    for (int j = 0; j < 8; ++j) vv[j] = T[t][c8 * 8 + j];
    *(u16x8*)&ab[c8 * 8] = vv;
  }
}

// ---------------------------------------------------------------- K3
// out[n,d] = gamma * sum_c x[n,c]*attn[c,d] + x[n,d].
// Per WG: 128n x 256d, K=256 in 8 steps of 32.  grid = 32*32 = 1024.
// A: reg-staged f32->bf16 (packed cvt) into swizzled LDS [128][32].
// B: global_load_lds from attnT into swizzled LDS [256][32].
__global__ __launch_bounds__(256, 2) void k3_av(
    const float* __restrict__ x, const unsigned short* __restrict__ attnT,
    const float* __restrict__ gamma, float* __restrict__ out) {
  __shared__ __align__(16) unsigned short A_s[2][128 * 32];
  __shared__ __align__(16) unsigned short B_s[2][256 * 32];

  int dd = blockIdx.x;
  int b  = (dd & 7) + 8 * ((dd >> 3) >> 5);   // XCD swizzle for L2 locality
  int mt = (dd >> 3) & 31;
  int n0 = mt << 7;
  const float* xb = x + ((size_t)b << 20);
  const unsigned short* ab = attnT + ((size_t)b << 16);
  float* ob = out + ((size_t)b << 20);

  int t = threadIdx.x, w = t >> 6, l = t & 63;
  int wm = w >> 1, wn = w & 1;
  int fr = l & 15, fh = l >> 4;

  int ar = t >> 1, ah = t & 1;             // A staging: row, half
  const float* aSrc = xb + (size_t)(n0 + ar) * 256 + ah * 16;
  int brow = l >> 2;                       // B staging: row in 16-row segment
  int bhi = (l & 3) ^ (brow & 3);          // pre-swizzled 16B slot

  f32x4 acc[4][8];
#pragma unroll
  for (int m = 0; m < 4; ++m)
#pragma unroll
    for (int n = 0; n < 8; ++n) acc[m][n] = (f32x4)(0.0f);

  auto STAGE_A = [&](int bsel, int k0) {
    uint32_t pk[8];
#pragma unroll
    for (int q = 0; q < 4; ++q) {
      fl4 vv = *(const fl4*)&aSrc[k0 + q * 4];
      pk[2 * q]     = cvtpk(vv.x, vv.y);
      pk[2 * q + 1] = cvtpk(vv.z, vv.w);
    }
#pragma unroll
    for (int j = 0; j < 2; ++j) {
      int hi = ah * 2 + j;
      int byt = ar * 64 + ((hi ^ (ar & 3)) << 4);
      *(u32x4*)&A_s[bsel][byt >> 1] =
          u32x4{pk[4 * j], pk[4 * j + 1], pk[4 * j + 2], pk[4 * j + 3]};
    }
  };

  auto STAGE_B = [&](int bsel, int k0) {
#pragma unroll
    for (int r = 0; r < 4; ++r) {
      int seg = r * 4 + w;                 // 16 segments of 16 rows
      int row = seg * 16 + brow;
      gload16(&ab[(size_t)row * 256 + k0 + bhi * 8], &B_s[bsel][seg * 512]);
    }
  };

  STAGE_A(0, 0);
  STAGE_B(0, 0);
  __syncthreads();

  int buf = 0;
#pragma unroll 1
  for (int kt = 0; kt < 8; ++kt) {
    if (kt < 7) { STAGE_A(buf ^ 1, (kt + 1) * 32); STAGE_B(buf ^ 1, (kt + 1) * 32); }
    bf16x8s af[4];
#pragma unroll
    for (int m = 0; m < 4; ++m) {
      int row = wm * 64 + m * 16 + fr;
      int byt = row * 64 + ((fh ^ (row & 3)) << 4);
      af[m] = *(const bf16x8s*)&A_s[buf][byt >> 1];
    }
    bf16x8s bfv[8];
#pragma unroll
    for (int n = 0; n < 8; ++n) {
      int dn = wn * 128 + n * 16 + fr;
      int byt = dn * 64 + ((fh ^ (dn & 3)) << 4);
      bfv[n] = *(const bf16x8s*)&B_s[buf][byt >> 1];
    }
#pragma unroll
    for (int m = 0; m < 4; ++m)
#pragma unroll
      for (int n = 0; n < 8; ++n)
        acc[m][n] = __builtin_amdgcn_mfma_f32_16x16x32_bf16(
            af[m], bfv[n], acc[m][n], 0, 0, 0);
    __syncthreads();
    buf ^= 1;
  }

  float g = gamma[0];
#pragma unroll
  for (int m = 0; m < 4; ++m) {
    int row = wm * 64 + m * 16 + fh * 4;
#pragma unroll
    for (int n = 0; n < 8; ++n) {
      int col = wn * 128 + n * 16 + fr;
#pragma unroll
      for (int i = 0; i < 4; ++i) {
        size_t idx = (size_t)(n0 + row + i) * 256 + col;
        ob[idx] = g * acc[m][n][i] + xb[idx];
      }
    }
  }
}

// ---------------------------------------------------------------- launch
extern "C" void kernel_launch(void* const* d_in, const int* in_sizes, int n_in,
                              void* d_out, int out_size, void* d_ws, size_t ws_size,
                              hipStream_t stream) {
  const float* x     = (const float*)d_in[0];
  const float* gamma = (const float*)d_in[1];
  float* out = (float*)d_out;

  // scratch layout: bf16 partials (32MB) live in d_out[64MB..96MB) (dead
  // before K3 rewrites it); attnT (4MB) in d_ws (K3 reads it while writing
  // d_out).
  unsigned short* part  = (unsigned short*)((char*)d_out + (size_t)64 * 1024 * 1024);
  unsigned short* attnT = (unsigned short*)d_ws;

  k1_ata<<<256, 512, 0, stream>>>(x, part);
  k2_softmax<<<128, 256, 0, stream>>>(part, attnT);
  k3_av<<<1024, 256, 0, stream>>>(x, attnT, gamma, out);
}

// Round 9
// 110.848 us; speedup vs baseline: 1.3665x; 1.0155x over previous
//
#include <hip/hip_runtime.h>
#include <hip/hip_bf16.h>
#include <stdint.h>

// CAM: out = gamma * (A @ softmax(A^T A)) + x,  A = x.reshape(B, N, C)
// B=32, N=4096 (64*64), C=256.
// Pipeline:
//   K1: symmetric aTa, splitK=8; one WG per (b,ks) stages a 256c x 64n slab
//       per kt with coalesced row loads + in-lane transpose -> swizzled LDS;
//       tile is BOTH MFMA operands.  bf16 partials (32MB) -> d_out[64MB..96MB)
//   K2: reduce 8 bf16 partials + softmax + transpose -> attnT bf16 (d_ws, 4MB)
//   K3: out = gamma * (A @ attn) + x.  128x128 tile, 4 blocks/CU, nt stores.

typedef __attribute__((ext_vector_type(8))) short bf16x8s;
typedef __attribute__((ext_vector_type(8))) unsigned short u16x8;
typedef __attribute__((ext_vector_type(4))) unsigned short u16x4;
typedef __attribute__((ext_vector_type(4))) float f32x4;
typedef __attribute__((ext_vector_type(4))) float fl4;
typedef __attribute__((ext_vector_type(4))) uint32_t u32x4;

__device__ __forceinline__ unsigned short f2bf(float f) {
  union { float f; uint32_t u; } v; v.f = f;
  uint32_t r = v.u + 0x7FFFu + ((v.u >> 16) & 1u);
  return (unsigned short)(r >> 16);
}

__device__ __forceinline__ float bf2f(unsigned short h) {
  union { float f; uint32_t u; } v; v.u = ((uint32_t)h) << 16; return v.f;
}

// packed f32 pair -> 2x bf16 in one u32 (low = lo), RNE
__device__ __forceinline__ uint32_t cvtpk(float lo, float hi) {
  __hip_bfloat162 h = __float22bfloat162_rn(float2{lo, hi});
  union { __hip_bfloat162 h; uint32_t u; } v; v.h = h; return v.u;
}

__device__ __forceinline__ void gload16(const void* g, void* l) {
  __builtin_amdgcn_global_load_lds(
      (const __attribute__((address_space(1))) uint32_t*)g,
      (__attribute__((address_space(3))) uint32_t*)l, 16, 0, 0);
}

// ---------------------------------------------------------------- K1
// aTa[c,d] = sum_n x[n,c]*x[n,d] (symmetric): stage ONE 256c x 64n bf16 tile,
// use it as both A and B.  Per WG (512 thr, 8 waves): full 256x256 output,
// K-slab of 512 (splitK=8).  grid = 32*8 = 256 (1/CU); x read exactly once.
// Staging per kt: wave w, instr j: lane l loads fl4 at (row w*8+j, col 4l)
// -> 1KB fully-coalesced row per instruction; lane reg-transposes its 8n x 4c
// block, cvtpk -> 4x ds_write_b128 into XOR-swizzled LDS
// ([256 c][64 n] bf16, byte ^= (row&7)<<4).  T14: LOAD(kt+1)->MFMA->WRITE->bar.
// Partials stored BF16 (logit gap diag-offdiag ~3900 -> softmax insensitive).
__global__ __launch_bounds__(512, 2) void k1_ata(
    const float* __restrict__ x, unsigned short* __restrict__ part) {
  __shared__ __align__(16) unsigned short S[2][256 * 64];

  int bid = blockIdx.x;                 // 0..255
  int b = bid >> 3, ks = bid & 7;
  const float* xb = x + ((size_t)b << 20);
  const int nsl = ks * 512;

  int t = threadIdx.x, w = t >> 6, l = t & 63;
  int wm = w >> 1, wn = w & 1;          // 4x2 wave grid: 64-row x 128-col
  int fr = l & 15, fh = l >> 4;

  f32x4 acc[4][8];
#pragma unroll
  for (int m = 0; m < 4; ++m)
#pragma unroll
    for (int n = 0; n < 8; ++n) acc[m][n] = (f32x4)(0.0f);

  fl4 v[8];                             // rows w*8+j, cols [4l,4l+4)
  auto LOAD = [&](int kt) {
    const float* s0 = xb + (size_t)(nsl + kt * 64 + w * 8) * 256 + 4 * l;
#pragma unroll
    for (int j = 0; j < 8; ++j) v[j] = *(const fl4*)&s0[(size_t)j * 256];
  };
  auto WRITE = [&](int bsel) {
#pragma unroll
    for (int i = 0; i < 4; ++i) {
      int c = 4 * l + i;
      uint32_t w0 = cvtpk(v[0][i], v[1][i]);
      uint32_t w1 = cvtpk(v[2][i], v[3][i]);
      uint32_t w2 = cvtpk(v[4][i], v[5][i]);
      uint32_t w3 = cvtpk(v[6][i], v[7][i]);
      int byt = c * 128 + ((w * 16) ^ ((c & 7) << 4));
      *(u32x4*)&S[bsel][byt >> 1] = u32x4{w0, w1, w2, w3};
    }
  };

  LOAD(0);
  WRITE(0);
  __syncthreads();

#pragma unroll 1
  for (int kt = 0; kt < 8; ++kt) {
    if (kt < 7) LOAD(kt + 1);
    const unsigned short* Sb = S[kt & 1];
#pragma unroll
    for (int h = 0; h < 2; ++h) {
      bf16x8s afr[4], bfr[8];
#pragma unroll
      for (int m = 0; m < 4; ++m) {
        int row = wm * 64 + m * 16 + fr;
        int byt = row * 128 + ((h * 64 + fh * 16) ^ ((row & 7) << 4));
        afr[m] = *(const bf16x8s*)&Sb[byt >> 1];
      }
#pragma unroll
      for (int n = 0; n < 8; ++n) {
        int row = wn * 128 + n * 16 + fr;
        int byt = row * 128 + ((h * 64 + fh * 16) ^ ((row & 7) << 4));
        bfr[n] = *(const bf16x8s*)&Sb[byt >> 1];
      }
#pragma unroll
      for (int m = 0; m < 4; ++m)
#pragma unroll
        for (int n = 0; n < 8; ++n)
          acc[m][n] = __builtin_amdgcn_mfma_f32_16x16x32_bf16(
              afr[m], bfr[n], acc[m][n], 0, 0, 0);
    }
    if (kt < 7) WRITE((kt + 1) & 1);
    __syncthreads();
  }

  unsigned short* pb = part + ((size_t)bid << 16);  // bid = b*8+ks, 128KB bf16
#pragma unroll
  for (int m = 0; m < 4; ++m) {
    int row = wm * 64 + m * 16 + fh * 4;
#pragma unroll
    for (int n = 0; n < 8; ++n) {
      int col = wn * 128 + n * 16 + fr;
#pragma unroll
      for (int i = 0; i < 4; ++i)
        pb[(size_t)(row + i) * 256 + col] = f2bf(acc[m][n][i]);
    }
  }
}

// ---------------------------------------------------------------- K2
// sum 8 bf16 split-K partials, softmax over d, write attnT[b][d][c] (bf16).
// grid = 32*4 = 128 blocks (64 c-rows each), 256 threads (4 waves).
// Lane l owns cols 4l..4l+3 -> u16x4 contiguous loads (512B/wave/instr).
__global__ __launch_bounds__(256) void k2_softmax(
    const unsigned short* __restrict__ part, unsigned short* __restrict__ attnT) {
  __shared__ unsigned short T[256][66];
  int d = blockIdx.x;
  int b    = (d & 7) + 8 * ((d >> 3) >> 2);
  int cblk = (d >> 3) & 3;
  int t = threadIdx.x, w = t >> 6, l = t & 63;
  const unsigned short* pb =
      part + ((size_t)(b * 8) << 16) + (size_t)(cblk * 64) * 256 + 4 * l;

  for (int it = 0; it < 16; ++it) {
    int c = w * 16 + it;                   // local row 0..63
    float s[4] = {0.f, 0.f, 0.f, 0.f};
#pragma unroll
    for (int k = 0; k < 8; ++k) {
      u16x4 vv = *(const u16x4*)&pb[((size_t)k << 16) + (size_t)c * 256];
#pragma unroll
      for (int i = 0; i < 4; ++i) s[i] += bf2f(vv[i]);
    }
    float mx = fmaxf(fmaxf(s[0], s[1]), fmaxf(s[2], s[3]));
    for (int off = 32; off; off >>= 1) mx = fmaxf(mx, __shfl_xor(mx, off));
    float sum = 0.0f;
#pragma unroll
    for (int i = 0; i < 4; ++i) { s[i] = __expf(s[i] - mx); sum += s[i]; }
    for (int off = 32; off; off >>= 1) sum += __shfl_xor(sum, off);
    float inv = 1.0f / sum;
#pragma unroll
    for (int i = 0; i < 4; ++i) T[4 * l + i][c] = f2bf(s[i] * inv);
  }
  __syncthreads();

  unsigned short* ab = attnT + ((size_t)b << 16) + (size_t)t * 256 + cblk * 64;
#pragma unroll
  for (int c8 = 0; c8 < 8; ++c8) {
    u16x8 vv;
#pragma unroll
    for (int j = 0; j < 8; ++j) vv[j] = T[t][c8 * 8 + j];
    *(u16x8*)&ab[c8 * 8] = vv;
  }
}

// ---------------------------------------------------------------- K3
// out[n,d] = gamma * sum_c x[n,c]*attn[c,d] + x[n,d].
// Per WG: 128n x 128d, K=256 in 8 steps of 32.  grid = 32*64 = 2048,
// 256 threads (4 waves, 2x2), acc[4][4] -> 4 blocks/CU (launch_bounds 256,4).
// A: reg-staged f32->bf16 into swizzled LDS [128][32];
// B: global_load_lds from attnT into swizzled LDS [128][32].
// XCD-swizzled: the two d-tiles of an (b, n-tile) pair are co-XCD, so the
// second A-panel read is L2-hot; attnT (128KB/batch) L2-resident.
// out stored non-temporally (write-once) to keep x lines in L2 for the
// epilogue residual read.
__global__ __launch_bounds__(256, 4) void k3_av(
    const float* __restrict__ x, const unsigned short* __restrict__ attnT,
    const float* __restrict__ gamma, float* __restrict__ out) {
  __shared__ __align__(16) unsigned short A_s[2][128 * 32];
  __shared__ __align__(16) unsigned short B_s[2][128 * 32];

  int dd = blockIdx.x;
  int xcd = dd & 7, slot = dd >> 3;        // slot 0..255
  int b = xcd + 8 * (slot >> 6);           // 4 batches per XCD
  int inner = slot & 63;
  int mt = inner >> 1, dt = inner & 1;     // n-tile 0..31, d-tile 0..1
  int n0 = mt << 7, d0 = dt << 7;
  const float* xb = x + ((size_t)b << 20);
  const unsigned short* ab = attnT + ((size_t)b << 16);
  float* ob = out + ((size_t)b << 20);

  int t = threadIdx.x, w = t >> 6, l = t & 63;
  int wm = w >> 1, wn = w & 1;
  int fr = l & 15, fh = l >> 4;

  int ar = t >> 1, ah = t & 1;             // A staging: row, half
  const float* aSrc = xb + (size_t)(n0 + ar) * 256 + ah * 16;
  int brow = l >> 2;                       // B staging: row in 16-row segment
  int bhi = (l & 3) ^ (brow & 3);          // pre-swizzled 16B slot

  f32x4 acc[4][4];
#pragma unroll
  for (int m = 0; m < 4; ++m)
#pragma unroll
    for (int n = 0; n < 4; ++n) acc[m][n] = (f32x4)(0.0f);

  auto STAGE_A = [&](int bsel, int k0) {
    uint32_t pk[8];
#pragma unroll
    for (int q = 0; q < 4; ++q) {
      fl4 vv = *(const fl4*)&aSrc[k0 + q * 4];
      pk[2 * q]     = cvtpk(vv.x, vv.y);
      pk[2 * q + 1] = cvtpk(vv.z, vv.w);
    }
#pragma unroll
    for (int j = 0; j < 2; ++j) {
      int hi = ah * 2 + j;
      int byt = ar * 64 + ((hi ^ (ar & 3)) << 4);
      *(u32x4*)&A_s[bsel][byt >> 1] =
          u32x4{pk[4 * j], pk[4 * j + 1], pk[4 * j + 2], pk[4 * j + 3]};
    }
  };

  auto STAGE_B = [&](int bsel, int k0) {
#pragma unroll
    for (int r = 0; r < 2; ++r) {
      int seg = r * 4 + w;                 // 8 segments of 16 rows
      int row = d0 + seg * 16 + brow;
      gload16(&ab[(size_t)row * 256 + k0 + bhi * 8], &B_s[bsel][seg * 512]);
    }
  };

  STAGE_A(0, 0);
  STAGE_B(0, 0);
  __syncthreads();

  int buf = 0;
#pragma unroll 1
  for (int kt = 0; kt < 8; ++kt) {
    if (kt < 7) { STAGE_A(buf ^ 1, (kt + 1) * 32); STAGE_B(buf ^ 1, (kt + 1) * 32); }
    bf16x8s af[4];
#pragma unroll
    for (int m = 0; m < 4; ++m) {
      int row = wm * 64 + m * 16 + fr;
      int byt = row * 64 + ((fh ^ (row & 3)) << 4);
      af[m] = *(const bf16x8s*)&A_s[buf][byt >> 1];
    }
    bf16x8s bfv[4];
#pragma unroll
    for (int n = 0; n < 4; ++n) {
      int dn = wn * 64 + n * 16 + fr;
      int byt = dn * 64 + ((fh ^ (dn & 3)) << 4);
      bfv[n] = *(const bf16x8s*)&B_s[buf][byt >> 1];
    }
#pragma unroll
    for (int m = 0; m < 4; ++m)
#pragma unroll
      for (int n = 0; n < 4; ++n)
        acc[m][n] = __builtin_amdgcn_mfma_f32_16x16x32_bf16(
            af[m], bfv[n], acc[m][n], 0, 0, 0);
    __syncthreads();
    buf ^= 1;
  }

  float g = gamma[0];
#pragma unroll
  for (int m = 0; m < 4; ++m) {
    int row = wm * 64 + m * 16 + fh * 4;
#pragma unroll
    for (int n = 0; n < 4; ++n) {
      int col = d0 + wn * 64 + n * 16 + fr;
#pragma unroll
      for (int i = 0; i < 4; ++i) {
        size_t idx = (size_t)(n0 + row + i) * 256 + col;
        __builtin_nontemporal_store(g * acc[m][n][i] + xb[idx], &ob[idx]);
      }
    }
  }
}

// ---------------------------------------------------------------- launch
extern "C" void kernel_launch(void* const* d_in, const int* in_sizes, int n_in,
                              void* d_out, int out_size, void* d_ws, size_t ws_size,
                              hipStream_t stream) {
  const float* x     = (const float*)d_in[0];
  const float* gamma = (const float*)d_in[1];
  float* out = (float*)d_out;

  // scratch layout: bf16 partials (32MB) live in d_out[64MB..96MB) (dead
  // before K3 rewrites it); attnT (4MB) in d_ws (K3 reads it while writing
  // d_out).
  unsigned short* part  = (unsigned short*)((char*)d_out + (size_t)64 * 1024 * 1024);
  unsigned short* attnT = (unsigned short*)d_ws;

  k1_ata<<<256, 512, 0, stream>>>(x, part);
  k2_softmax<<<128, 256, 0, stream>>>(part, attnT);
  k3_av<<<2048, 256, 0, stream>>>(x, attnT, gamma, out);
}